// Round 6
// baseline (43411.859 us; speedup 1.0000x reference)
//
#include <hip/hip_runtime.h>

// ESN recurrence on MI355X — R10: flag-gated register-direct fp16 pipeline.
// T=4096 steps, B=64, I=128, H=1024. out = h_T [64,1024] fp32.
//
// 64 blocks x 256 threads (4 waves), geometry/publish/weights R9-verbatim.
// Composition of HW-proven parts:
//  * R4's cheap FLAG poll (1 dword/lane/round) gates the expensive data
//    loads — fixes R9's regression (data-load-as-poll cost 8MB of LLC
//    service per retry round, ~2 wasted rounds/step).
//  * R9's register-direct tagged A-fragment consume: one dwordx4 per MFMA
//    fragment straight from LLC; no h_lds, no barriers, no LDS at all.
//  * R9's tag check + bounded retry net stays as a rare-case safety net,
//    letting producers fire-and-forget data then flag (no store-ack RT);
//    tags catch data-after-flag reordering.
//  * x per-wave in registers; x-conversion BEFORE h-load issue so the
//    compiler's xf wait can't drain the h loads (R9's hidden serializer).
// Safety: wave at step t+1 needs all peer flags >= t+1, stored only after
// those peers' step-t reads completed -> no buffer-parity overwrite race;
// tag generations (1,1,0,0 over steps) guard the reorder window.

#define TT 4096
#define BB 64
#define II 128
#define HH 1024
#define TAGBIT 0x40000000u

typedef _Float16 f16x8 __attribute__((ext_vector_type(8)));
typedef float f32x4 __attribute__((ext_vector_type(4)));
typedef unsigned int u32x4 __attribute__((ext_vector_type(4)));

static __device__ __forceinline__ unsigned short f2h_bits(float f) {
    _Float16 h = (_Float16)f;          // v_cvt_f16_f32 (RNE)
    return __builtin_bit_cast(unsigned short, h);
}

// R5/R9-hardware-proven vaddr-form global ops (64-bit pointer in VGPR pair).
static __device__ __forceinline__ u32x4 gload16_sc1(const unsigned int* p) {
    u32x4 r;
    asm volatile("global_load_dwordx4 %0, %1, off sc1"
                 : "=v"(r) : "v"(p) : "memory");
    return r;
}
static __device__ __forceinline__ void gstore4_sc1(unsigned int* p, unsigned int v) {
    asm volatile("global_store_dword %0, %1, off sc1"
                 :: "v"(p), "v"(v) : "memory");
}

// full drain + scheduler fence (rule #18)
#define WAITV0()                                              \
    asm volatile("s_waitcnt vmcnt(0)" ::: "memory");          \
    __builtin_amdgcn_sched_barrier(0)

// tag-check fragment kt (R9-verbatim); pass: clear tags + 1 MFMA; fail: FAIL.
#define CHECK_TILE(kt, FAIL)                                                  \
    {                                                                         \
        u32x4 v = hf[kt];                                                     \
        unsigned int bad = (v[0] ^ etag) | (v[1] ^ etag) |                    \
                           (v[2] ^ etag) | (v[3] ^ etag);                     \
        if (__ballot((bad & TAGBIT) == 0u) == ~0ull) {                        \
            v &= 0xBFFFFFFFu;                                                 \
            f16x8 a = __builtin_bit_cast(f16x8, v);                           \
            (((kt) & 1) ? acc1 : acc0) =                                      \
                __builtin_amdgcn_mfma_f32_16x16x32_f16(                       \
                    a, wh[kt], (((kt) & 1) ? acc1 : acc0), 0, 0, 0);          \
        } else { FAIL; }                                                      \
    }

__global__ __launch_bounds__(256, 1) void esn_kernel(
    const float* __restrict__ x, const float* __restrict__ wih,
    const float* __restrict__ whh, const float* __restrict__ bih,
    const float* __restrict__ bhh, float* __restrict__ out,
    unsigned int* __restrict__ hbu0, unsigned int* __restrict__ hbu1,
    unsigned int* __restrict__ flags)
{
    const int tid  = threadIdx.x;
    const int lane = tid & 63;
    const int wv   = tid >> 6;
    const int col  = lane & 15;     // MFMA col (n) / A row (m)
    const int quad = lane >> 4;

    const int blk    = blockIdx.x;          // 0..63
    const int m      = blk >> 4;            // batch group 0..3
    const int m_base = m * 16;
    const int jj     = blk & 15;            // chunk index within group
    const int n_idx  = jj * 4 + wv;
    const int n_base = n_idx * 16;

    // ---- one-time: weights into registers as fp16 (R9-verbatim) ----
    f16x8 wh[32], wi[4];
#pragma unroll
    for (int kt = 0; kt < 32; ++kt) {
        const float* p = whh + (size_t)(n_base + col) * HH + kt * 32 + quad * 8;
        f16x8 w;
#pragma unroll
        for (int j = 0; j < 8; ++j) w[j] = (_Float16)p[j];
        wh[kt] = w;
    }
#pragma unroll
    for (int kt = 0; kt < 4; ++kt) {
        const float* p = wih + (size_t)(n_base + col) * II + kt * 32 + quad * 8;
        f16x8 w;
#pragma unroll
        for (int j = 0; j < 8; ++j) w[j] = (_Float16)p[j];
        wi[kt] = w;
    }
    const float bias_sum = bih[n_base + col] + bhh[n_base + col];

    // x per-lane A-frag base: row m_base+col, k-cols quad*8..
    const float* xbase = x + (size_t)(m_base + col) * II + quad * 8;
    // per-wave flag slots: consumer polls flags[m*64 + lane] (lane == jj*4+wv
    // of the producer wave); producer lane 0 stores flags[m*64 + jj*4 + wv].
    const unsigned int* fpoll = flags + m * 64 + lane;
    unsigned int*       fpub  = flags + m * 64 + jj * 4 + wv;

    // prefetch x_0 (plain loads; compiler-managed waits — R9-proven class)
    f32x4 xf[8];
#pragma unroll
    for (int kt = 0; kt < 4; ++kt) {
        xf[2 * kt]     = *(const f32x4*)(xbase + kt * 32);
        xf[2 * kt + 1] = *(const f32x4*)(xbase + kt * 32 + 4);
    }

    u32x4 hf[32];
    for (int t = 0; t < TT; ++t) {
        const unsigned int* rbu = (t & 1) ? hbu1 : hbu0;
        unsigned int*       wbu = (t & 1) ? hbu0 : hbu1;
        // tag generations 1,1,0,0,... ; zero-init = tag 0 (R9-verbatim)
        const unsigned int etag =
            (t == 0) ? 0u : ((1u ^ (((unsigned)(t - 1) >> 1) & 1u)) << 30);
        const unsigned int my_tag = (1u ^ (((unsigned)t >> 1) & 1u)) << 30;

        // (1) cheap flag poll: all 64 lanes, one sc1 dword per round.
        //     Flag f means "h^f published". Need h^t -> f >= t. t=0: 0>=0 ok.
        for (;;) {
            unsigned int v;
            asm volatile("global_load_dword %0, %1, off sc1\n\t"
                         "s_waitcnt vmcnt(0)"
                         : "=v"(v) : "v"(fpoll) : "memory");
            if (__ballot(v >= (unsigned int)t) == ~0ull) break;
        }
        // poll's vmcnt(0) also drained last step's x prefetch + publishes.

        // (2) convert x_t -> A-frags BEFORE issuing h loads (so no compiler
        //     wait lands between the h issue and WAITV0 — R9's serializer).
        f16x8 xa[4];
#pragma unroll
        for (int kt = 0; kt < 4; ++kt) {
            f16x8 a;
#pragma unroll
            for (int j = 0; j < 4; ++j) {
                a[j]     = (_Float16)xf[2 * kt][j];
                a[4 + j] = (_Float16)xf[2 * kt + 1][j];
            }
            xa[kt] = a;
        }

        // (3) issue all 32 h-fragment loads (guaranteed-fresh modulo rare
        //     data-after-flag reorder; R9-verbatim proven addressing)
        const unsigned int* hb =
            rbu + (size_t)(m * 16) * 512 + col * 32 + quad * 4;
#pragma unroll
        for (int kt = 0; kt < 32; ++kt)
            hf[kt] = gload16_sc1(hb + (kt >> 1) * 512 + (kt & 1) * 16);

        // (4) x MFMAs fill part of the h-RT shadow (pure register ops)
        f32x4 acc0 = {0.f, 0.f, 0.f, 0.f};
        f32x4 acc1 = {0.f, 0.f, 0.f, 0.f};
#pragma unroll
        for (int kt = 0; kt < 4; ++kt)
            ((kt & 1) ? acc1 : acc0) =
                __builtin_amdgcn_mfma_f32_16x16x32_f16(
                    xa[kt], wi[kt], ((kt & 1) ? acc1 : acc0), 0, 0, 0);

        // (5) single data RT, then x_{t+1} prefetch rides under checks/publish
        WAITV0();
        if (t + 1 < TT) {
            const float* p = xbase + (size_t)(t + 1) * (BB * II);
#pragma unroll
            for (int kt = 0; kt < 4; ++kt) {
                xf[2 * kt]     = *(const f32x4*)(p + kt * 32);
                xf[2 * kt + 1] = *(const f32x4*)(p + kt * 32 + 4);
            }
        }

        unsigned int mask = 0;
#pragma unroll
        for (int kt = 0; kt < 32; ++kt) CHECK_TILE(kt, mask |= (1u << kt))

        // (6) rare-case retry net (R9-verbatim; bounded + poison)
        mask = __builtin_amdgcn_readfirstlane(mask);
        int rounds = 0;
        while (mask && rounds < 65536) {
#pragma unroll
            for (int kt = 0; kt < 32; ++kt)
                if (mask & (1u << kt))
                    hf[kt] = gload16_sc1(hb + (kt >> 1) * 512 + (kt & 1) * 16);
            WAITV0();
            unsigned int nm = 0;
#pragma unroll
            for (int kt = 0; kt < 32; ++kt)
                if (mask & (1u << kt))
                    CHECK_TILE(kt, nm |= (1u << kt))
            mask = __builtin_amdgcn_readfirstlane(nm);
            ++rounds;
        }
        if (mask) acc0[0] += 1e30f;   // protocol failure -> loud, never hung

        // (7) epilogue: bias + tanh
        float th[4];
#pragma unroll
        for (int i = 0; i < 4; ++i) {
            float pre = acc0[i] + acc1[i] + bias_sum;
            float pc  = fminf(fmaxf(pre, -9.f), 9.f);
            float e2  = __expf(2.f * pc);
            th[i] = (e2 - 1.f) / (e2 + 1.f);
        }

        if (t == TT - 1) {
#pragma unroll
            for (int i = 0; i < 4; ++i)
                out[(size_t)(m_base + quad * 4 + i) * HH + n_base + col] = th[i];
        } else {
            // (8) publish — R9-verbatim tagged scattered dword sc1 stores,
            //     then flag (fire-and-forget; tags cover reordering).
            unsigned int p01 = (unsigned int)f2h_bits(th[0]) |
                               ((unsigned int)f2h_bits(th[1]) << 16);
            unsigned int p23 = (unsigned int)f2h_bits(th[2]) |
                               ((unsigned int)f2h_bits(th[3]) << 16);
            unsigned int q01 = (unsigned int)__shfl_xor((int)p01, 1, 64);
            unsigned int q23 = (unsigned int)__shfl_xor((int)p23, 1, 64);
            if (!(lane & 1)) {
                unsigned int w0 = ((p01 & 0xFFFFu) | (q01 << 16)) | my_tag;
                unsigned int w1 = ((p01 >> 16) | (q01 & 0xFFFF0000u)) | my_tag;
                unsigned int w2 = ((p23 & 0xFFFFu) | (q23 << 16)) | my_tag;
                unsigned int w3 = ((p23 >> 16) | (q23 & 0xFFFF0000u)) | my_tag;
                unsigned int* bp = wbu + (size_t)(m * 16 + jj) * 512
                                   + wv * 8 + (col >> 1);
                gstore4_sc1(bp + (quad * 4 + 0) * 32, w0);
                gstore4_sc1(bp + (quad * 4 + 1) * 32, w1);
                gstore4_sc1(bp + (quad * 4 + 2) * 32, w2);
                gstore4_sc1(bp + (quad * 4 + 3) * 32, w3);
            }
            if (lane == 0) {
                unsigned int fv = (unsigned int)(t + 1);
                gstore4_sc1(fpub, fv);
            }
        }
    }
}

extern "C" void kernel_launch(void* const* d_in, const int* in_sizes, int n_in,
                              void* d_out, int out_size, void* d_ws, size_t ws_size,
                              hipStream_t stream) {
    const float* x   = (const float*)d_in[0];
    const float* wih = (const float*)d_in[1];
    const float* whh = (const float*)d_in[2];
    const float* bih = (const float*)d_in[3];
    const float* bhh = (const float*)d_in[4];
    float* out = (float*)d_out;

    unsigned int* hbu0  = (unsigned int*)d_ws;                     // 128 KB
    unsigned int* hbu1  = hbu0 + 32768;                            // 128 KB
    unsigned int* flags = (unsigned int*)((char*)d_ws + 262144);   // 256 u32

    // zero h buffers (h0 = 0, tag 0) + flags (ws is poisoned 0xAA)
    hipMemsetAsync(d_ws, 0, 262144 + 1024, stream);

    esn_kernel<<<dim3(64), dim3(256), 0, stream>>>(x, wih, whh, bih, bhh,
                                                   out, hbu0, hbu1, flags);
}

// Round 7
// 16155.293 us; speedup vs baseline: 2.6872x; 2.6872x over previous
//
#include <hip/hip_runtime.h>

// ESN recurrence on MI355X — R11: R4 structure verbatim, with the h/flag
// exchange moved from sc1 stores (measured: write-through to HBM, 542MB
// WRITE_SIZE + 2.5GB of consumer HBM misses -> every sync link at HBM
// latency) to device-scope atomicExch, which must execute at the LLC
// coherence point and leaves lines LLC-resident. Consumer staging loads
// stay sc1 (read at LLC -> now hit). Plus fp16 instead of bf16 hi/lo
// (72 -> 36 MFMAs/step, absmax 0.0098 -> 0.0039; byte layout identical so
// all staging/swizzle code is unchanged). Everything else — poll loop,
// x pipeline, LDS staging + swizzle, barriers, c_lds pack, ack ordering —
// is the hardware-validated R4 code unchanged.
// T=4096 steps, B=64, I=128, H=1024. out = h_T [64,1024] fp32.

#define TT 4096
#define BB 64
#define II 128
#define HH 1024

typedef _Float16 f16x8 __attribute__((ext_vector_type(8)));
typedef float f32x4 __attribute__((ext_vector_type(4)));
typedef unsigned int u32x4 __attribute__((ext_vector_type(4)));

static __device__ __forceinline__ unsigned short f2h_bits(float f) {
    _Float16 h = (_Float16)f;          // v_cvt_f16_f32 (RNE)
    return __builtin_bit_cast(unsigned short, h);
}

static __device__ __forceinline__ u32x4 gload16_sc1(const unsigned int* p) {
    u32x4 r;
    asm volatile("global_load_dwordx4 %0, %1, off sc1"
                 : "=v"(r) : "v"(p) : "memory");
    return r;
}

// 16B-chunk swizzle for h_lds (pitch 1032 shorts = 129 16B-chunks/row)
__device__ __forceinline__ int swz(int L) {
    return (L & 0x78) | (((L & 7) + (L >> 3)) & 7);
}

__global__ __launch_bounds__(256, 1) void esn_kernel(
    const float* __restrict__ x, const float* __restrict__ wih,
    const float* __restrict__ whh, const float* __restrict__ bih,
    const float* __restrict__ bhh, float* __restrict__ out,
    unsigned int* __restrict__ hbu0, unsigned int* __restrict__ hbu1,
    unsigned int* __restrict__ flags)
{
    __shared__ __align__(16) unsigned short h_lds[16 * 1032];  // 33 KB
    __shared__ __align__(16) unsigned short x_lds[16 * 136];   // 4.25 KB
    __shared__ __align__(16) unsigned int   c_lds[16 * 36];    // 2.25 KB

    const int tid  = threadIdx.x;
    const int lane = tid & 63;
    const int wv   = tid >> 6;
    const int col  = lane & 15;     // MFMA col (n) / A row (m)
    const int quad = lane >> 4;

    const int blk    = blockIdx.x;
    const int m      = blk >> 4;            // batch group 0..3
    const int m_base = m * 16;
    const int jj     = blk & 15;            // producer index within group
    const int n_idx  = jj * 4 + wv;
    const int n_base = n_idx * 16;

    // ---- one-time: weights into registers as fp16 (R4 addressing) ----
    f16x8 wh[32], wi[4];
#pragma unroll
    for (int kt = 0; kt < 32; ++kt) {
        const float* p = whh + (size_t)(n_base + col) * HH + kt * 32 + quad * 8;
        f16x8 w;
#pragma unroll
        for (int j = 0; j < 8; ++j) w[j] = (_Float16)p[j];
        wh[kt] = w;
    }
#pragma unroll
    for (int kt = 0; kt < 4; ++kt) {
        const float* p = wih + (size_t)(n_base + col) * II + kt * 32 + quad * 8;
        f16x8 w;
#pragma unroll
        for (int j = 0; j < 8; ++j) w[j] = (_Float16)p[j];
        wi[kt] = w;
    }
    const float bias_sum = bih[n_base + col] + bhh[n_base + col];

    const int sr = tid >> 4;          // x-staging row 0..15
    const int sc = tid & 15;          // x-staging col group 0..15
    const int csrc = tid >> 4;        // h chunk this thread loads 0..15
    const int crow = tid & 15;        // row within that chunk
    const unsigned int* fl = flags + m * 16;

    // x software pipeline: prefetch x_0 into registers (R4-verbatim)
    f32x4 xa, xb;
    {
        const float* gp = x + (size_t)(m_base + sr) * II + sc * 8;
        xa = *(const f32x4*)gp;
        xb = *(const f32x4*)(gp + 4);
    }

    for (int t = 0; t < TT; ++t) {
        const unsigned int* rbu = (t & 1) ? hbu1 : hbu0;
        unsigned int*       wbu = (t & 1) ? hbu0 : hbu1;

        // convert prefetched x_t -> fp16 -> LDS (R4-verbatim path, f16)
        {
            f16x8 v;
#pragma unroll
            for (int j = 0; j < 4; ++j) v[j] = (_Float16)xa[j];
#pragma unroll
            for (int j = 0; j < 4; ++j) v[4 + j] = (_Float16)xb[j];
            *(f16x8*)(x_lds + sr * 136 + sc * 8) = v;
        }

        // wait until every producer in this m-group has published h^t
        // (t=0: flags zeroed, v>=0 passes; hbu0 zeroed = h0)  [R4-verbatim]
        if (wv == 0) {
            const bool skip = (lane >= 16);
            const unsigned int* fp = fl + lane;
            for (;;) {
                unsigned int v = 0;
                if (!skip)
                    asm volatile("global_load_dword %0, %1, off sc1\n\t"
                                 "s_waitcnt vmcnt(0)"
                                 : "=v"(v) : "v"(fp) : "memory");
                if (__ballot(skip || v >= (unsigned int)t) == ~0ull) break;
            }
        }
        __syncthreads();

        // stage h^t: 16 chunks x 2KB, coalesced dwordx4 sc1 loads [R4]
        {
            const unsigned int* gp = rbu + (size_t)(m * 16 + csrc) * 512 + crow * 32;
            u32x4 a0 = gload16_sc1(gp);
            u32x4 a1 = gload16_sc1(gp + 4);
            u32x4 a2 = gload16_sc1(gp + 8);
            u32x4 a3 = gload16_sc1(gp + 12);
            u32x4 a4 = gload16_sc1(gp + 16);
            u32x4 a5 = gload16_sc1(gp + 20);
            u32x4 a6 = gload16_sc1(gp + 24);
            u32x4 a7 = gload16_sc1(gp + 28);
            asm volatile("s_waitcnt vmcnt(0)"
                         : "+v"(a0), "+v"(a1), "+v"(a2), "+v"(a3),
                           "+v"(a4), "+v"(a5), "+v"(a6), "+v"(a7)
                         :: "memory");
            unsigned short* lp = h_lds + crow * 1032;
            *(u32x4*)(lp + swz(csrc * 8 + 0) * 8) = a0;
            *(u32x4*)(lp + swz(csrc * 8 + 1) * 8) = a1;
            *(u32x4*)(lp + swz(csrc * 8 + 2) * 8) = a2;
            *(u32x4*)(lp + swz(csrc * 8 + 3) * 8) = a3;
            *(u32x4*)(lp + swz(csrc * 8 + 4) * 8) = a4;
            *(u32x4*)(lp + swz(csrc * 8 + 5) * 8) = a5;
            *(u32x4*)(lp + swz(csrc * 8 + 6) * 8) = a6;
            *(u32x4*)(lp + swz(csrc * 8 + 7) * 8) = a7;
        }
        __syncthreads();

        // prefetch x_{t+1} (fills during MFMA + epilogue)  [R4-verbatim]
        if (t + 1 < TT) {
            const float* gp = x + (size_t)(t + 1) * (BB * II)
                              + (size_t)(m_base + sr) * II + sc * 8;
            xa = *(const f32x4*)gp;
            xb = *(const f32x4*)(gp + 4);
        }

        // MFMAs: 32 h-tiles + 4 x-tiles, fp16, parity-split dual chains
        f32x4 acc0 = {0.f, 0.f, 0.f, 0.f};
        f32x4 acc1 = {0.f, 0.f, 0.f, 0.f};
        const unsigned short* arow = h_lds + col * 1032;
#pragma unroll
        for (int kt = 0; kt < 32; ++kt) {
            f16x8 a = *(const f16x8*)(arow + swz(kt * 4 + quad) * 8);
            ((kt & 1) ? acc1 : acc0) =
                __builtin_amdgcn_mfma_f32_16x16x32_f16(
                    a, wh[kt], ((kt & 1) ? acc1 : acc0), 0, 0, 0);
        }
        const unsigned short* xrow = x_lds + col * 136;
#pragma unroll
        for (int kt = 0; kt < 4; ++kt) {
            f16x8 a = *(const f16x8*)(xrow + kt * 32 + quad * 8);
            ((kt & 1) ? acc1 : acc0) =
                __builtin_amdgcn_mfma_f32_16x16x32_f16(
                    a, wi[kt], ((kt & 1) ? acc1 : acc0), 0, 0, 0);
        }

        // epilogue: bias + tanh; pack fp16 pairs into u32 -> c_lds [16][36]
        float th[4];
#pragma unroll
        for (int i = 0; i < 4; ++i) {
            float pre = acc0[i] + acc1[i] + bias_sum;
            float pc  = fminf(fmaxf(pre, -9.f), 9.f);
            float e   = __expf(2.f * pc);
            th[i] = (e - 1.f) / (e + 1.f);
        }
        {
            unsigned int p01 = (unsigned int)f2h_bits(th[0]) |
                               ((unsigned int)f2h_bits(th[1]) << 16);
            unsigned int p23 = (unsigned int)f2h_bits(th[2]) |
                               ((unsigned int)f2h_bits(th[3]) << 16);
            unsigned int q01 = (unsigned int)__shfl_xor((int)p01, 1, 64);
            unsigned int q23 = (unsigned int)__shfl_xor((int)p23, 1, 64);
            if (!(lane & 1)) {
                unsigned int w0 = (p01 & 0xFFFFu) | (q01 << 16);
                unsigned int w1 = (p01 >> 16) | (q01 & 0xFFFF0000u);
                unsigned int w2 = (p23 & 0xFFFFu) | (q23 << 16);
                unsigned int w3 = (p23 >> 16) | (q23 & 0xFFFF0000u);
                const int c = wv * 8 + (col >> 1);
                unsigned int* cl = c_lds + (quad * 4) * 36 + c;
                cl[0]      = w0;
                cl[36]     = w1;
                cl[2 * 36] = w2;
                cl[3 * 36] = w3;
            }
        }
        if (t == TT - 1) {
#pragma unroll
            for (int i = 0; i < 4; ++i)
                out[(size_t)(m_base + quad * 4 + i) * HH + n_base + col] = th[i];
        }
        __syncthreads();

        // publish this block's 2KB chunk via device-scope atomicExch:
        // executes at the LLC coherence point (no HBM write-through) and
        // leaves the lines LLC-resident for the consumers' sc1 loads.
        // 256 threads x 2 dwords = same 512-dword volume as R4.
        if (t < TT - 1) {
            const int r  = tid >> 4;          // 0..15
            const int c0 = (tid & 15) * 2;    // 0,2,..,30
            unsigned int* dst = wbu + (size_t)(m * 16 + jj) * 512 + r * 32 + c0;
            atomicExch(dst,     c_lds[r * 36 + c0]);
            atomicExch(dst + 1, c_lds[r * 36 + c0 + 1]);
            // ack at coherence point, then barrier, then flag (R4 ordering)
            asm volatile("s_waitcnt vmcnt(0)" ::: "memory");
            __syncthreads();
            if (tid == 0)
                atomicExch(&flags[m * 16 + jj], (unsigned int)(t + 1));
        }
    }
}

extern "C" void kernel_launch(void* const* d_in, const int* in_sizes, int n_in,
                              void* d_out, int out_size, void* d_ws, size_t ws_size,
                              hipStream_t stream) {
    const float* x   = (const float*)d_in[0];
    const float* wih = (const float*)d_in[1];
    const float* whh = (const float*)d_in[2];
    const float* bih = (const float*)d_in[3];
    const float* bhh = (const float*)d_in[4];
    float* out = (float*)d_out;

    unsigned int* hbu0  = (unsigned int*)d_ws;                      // 128 KB
    unsigned int* hbu1  = hbu0 + 32768;                             // 128 KB
    unsigned int* flags = (unsigned int*)((char*)d_ws + 262144);    // 64 u32

    // zero h buffer 0 (h0 = 0), buffer 1, and flags (ws is poisoned 0xAA)
    hipMemsetAsync(d_ws, 0, 262144 + 256, stream);

    esn_kernel<<<dim3(64), dim3(256), 0, stream>>>(x, wih, whh, bih, bhh,
                                                   out, hbu0, hbu1, flags);
}

// Round 9
// 15453.491 us; speedup vs baseline: 2.8092x; 1.0454x over previous
//
#include <hip/hip_runtime.h>

// ESN recurrence on MI355X — R13: R11 protocol VERBATIM + protocol-free wins.
// T=4096 steps, B=64, I=128, H=1024. out = h_T [64,1024] fp32.
//
// R11 (16.16 ms, passed) is the base; diffs are strictly non-protocol:
//  1. h_lds transposed to [k16][row] x 16B (no swizzle): stage writes hit
//     start-bank crow*4 (8 lanes per 4-bank group = ds_write_b128 minimum)
//     and MFMA reads hit start-bank col*4 (same minimum) -> removes the
//     measured 1.53e8 LDS bank-conflict cycles.
//  2. acc[4] accumulator chains: dependent-MFMA depth 36 -> 9.
//  3. Flags padded to 128B/line (SAME protocol/count/poll structure as R11;
//     only the stride changes) so 256 pollers + 16 atomic writers stop
//     colliding on 1-2 cache lines.
// Sync structure (wave-0 16-lane poll + ballot, block-wide barriers,
// atomicExch publish at LLC coherence point, ack -> barrier -> flag) is
// hardware-validated R11 code unchanged.

#define TT 4096
#define BB 64
#define II 128
#define HH 1024

typedef _Float16 f16x8 __attribute__((ext_vector_type(8)));
typedef float f32x4 __attribute__((ext_vector_type(4)));
typedef unsigned int u32x4 __attribute__((ext_vector_type(4)));

static __device__ __forceinline__ unsigned short f2h_bits(float f) {
    _Float16 h = (_Float16)f;          // v_cvt_f16_f32 (RNE)
    return __builtin_bit_cast(unsigned short, h);
}

static __device__ __forceinline__ u32x4 gload16_sc1(const unsigned int* p) {
    u32x4 r;
    asm volatile("global_load_dwordx4 %0, %1, off sc1"
                 : "=v"(r) : "v"(p) : "memory");
    return r;
}

__global__ __launch_bounds__(256, 1) void esn_kernel(
    const float* __restrict__ x, const float* __restrict__ wih,
    const float* __restrict__ whh, const float* __restrict__ bih,
    const float* __restrict__ bhh, float* __restrict__ out,
    unsigned int* __restrict__ hbu0, unsigned int* __restrict__ hbu1,
    unsigned int* __restrict__ flags)
{
    __shared__ __align__(16) unsigned short h_lds[128 * 16 * 8]; // 32 KB [k16][row]
    __shared__ __align__(16) unsigned short x_lds[16 * 136];     // 4.25 KB
    __shared__ __align__(16) unsigned int   c_lds[16 * 36];      // 2.25 KB

    const int tid  = threadIdx.x;
    const int lane = tid & 63;
    const int wv   = tid >> 6;
    const int col  = lane & 15;     // MFMA col (n) / A row (m)
    const int quad = lane >> 4;

    const int blk    = blockIdx.x;
    const int m      = blk >> 4;            // batch group 0..3
    const int m_base = m * 16;
    const int jj     = blk & 15;            // producer index within group
    const int n_idx  = jj * 4 + wv;
    const int n_base = n_idx * 16;

    // ---- one-time: weights into registers as fp16 (R11-verbatim) ----
    f16x8 wh[32], wi[4];
#pragma unroll
    for (int kt = 0; kt < 32; ++kt) {
        const float* p = whh + (size_t)(n_base + col) * HH + kt * 32 + quad * 8;
        f16x8 w;
#pragma unroll
        for (int j = 0; j < 8; ++j) w[j] = (_Float16)p[j];
        wh[kt] = w;
    }
#pragma unroll
    for (int kt = 0; kt < 4; ++kt) {
        const float* p = wih + (size_t)(n_base + col) * II + kt * 32 + quad * 8;
        f16x8 w;
#pragma unroll
        for (int j = 0; j < 8; ++j) w[j] = (_Float16)p[j];
        wi[kt] = w;
    }
    const float bias_sum = bih[n_base + col] + bhh[n_base + col];

    const int sr   = tid >> 4;        // x-staging row 0..15
    const int sc   = tid & 15;        // x-staging col group 0..15
    const int csrc = tid >> 4;        // h chunk this thread stages 0..15
    const int crow = tid & 15;        // row within that chunk
    // flags: one per (group, producer), padded 128B (32 dwords) apart
    const unsigned int* fl = flags + m * 512;   // + lane*32 in the poll

    // x software pipeline: prefetch x_0 into registers (R11-verbatim)
    f32x4 xa, xb;
    {
        const float* gp = x + (size_t)(m_base + sr) * II + sc * 8;
        xa = *(const f32x4*)gp;
        xb = *(const f32x4*)(gp + 4);
    }

    for (int t = 0; t < TT; ++t) {
        const unsigned int* rbu = (t & 1) ? hbu1 : hbu0;
        unsigned int*       wbu = (t & 1) ? hbu0 : hbu1;

        // (1) convert prefetched x_t -> fp16 -> x_lds (R11-verbatim)
        {
            f16x8 v;
#pragma unroll
            for (int j = 0; j < 4; ++j) v[j] = (_Float16)xa[j];
#pragma unroll
            for (int j = 0; j < 4; ++j) v[4 + j] = (_Float16)xb[j];
            *(f16x8*)(x_lds + sr * 136 + sc * 8) = v;
        }

        // (2) wait until every producer in this m-group has published h^t
        //     (t=0: flags zeroed, v>=0 passes; hbu0 zeroed = h0)
        //     R11-verbatim poll; only the flag stride changed (lane*32).
        if (wv == 0) {
            const bool skip = (lane >= 16);
            const unsigned int* fp = fl + lane * 32;
            for (;;) {
                unsigned int v = 0;
                if (!skip)
                    asm volatile("global_load_dword %0, %1, off sc1\n\t"
                                 "s_waitcnt vmcnt(0)"
                                 : "=v"(v) : "v"(fp) : "memory");
                if (__ballot(skip || v >= (unsigned int)t) == ~0ull) break;
            }
        }
        __syncthreads();

        // (3) stage h^t: 16 chunks x 2KB, coalesced dwordx4 sc1 loads ->
        //     transposed LDS [k16 = csrc*8+i][row = crow] (bank-balanced)
        {
            const unsigned int* gp = rbu + (size_t)(m * 16 + csrc) * 512 + crow * 32;
            u32x4 a0 = gload16_sc1(gp);
            u32x4 a1 = gload16_sc1(gp + 4);
            u32x4 a2 = gload16_sc1(gp + 8);
            u32x4 a3 = gload16_sc1(gp + 12);
            u32x4 a4 = gload16_sc1(gp + 16);
            u32x4 a5 = gload16_sc1(gp + 20);
            u32x4 a6 = gload16_sc1(gp + 24);
            u32x4 a7 = gload16_sc1(gp + 28);
            asm volatile("s_waitcnt vmcnt(0)"
                         : "+v"(a0), "+v"(a1), "+v"(a2), "+v"(a3),
                           "+v"(a4), "+v"(a5), "+v"(a6), "+v"(a7)
                         :: "memory");
            unsigned short* lp = h_lds + crow * 8;
            *(u32x4*)(lp + (csrc * 8 + 0) * 128) = a0;
            *(u32x4*)(lp + (csrc * 8 + 1) * 128) = a1;
            *(u32x4*)(lp + (csrc * 8 + 2) * 128) = a2;
            *(u32x4*)(lp + (csrc * 8 + 3) * 128) = a3;
            *(u32x4*)(lp + (csrc * 8 + 4) * 128) = a4;
            *(u32x4*)(lp + (csrc * 8 + 5) * 128) = a5;
            *(u32x4*)(lp + (csrc * 8 + 6) * 128) = a6;
            *(u32x4*)(lp + (csrc * 8 + 7) * 128) = a7;
        }
        __syncthreads();

        // (4) prefetch x_{t+1} (fills during MFMA + epilogue) [R11-verbatim]
        if (t + 1 < TT) {
            const float* gp = x + (size_t)(t + 1) * (BB * II)
                              + (size_t)(m_base + sr) * II + sc * 8;
            xa = *(const f32x4*)gp;
            xb = *(const f32x4*)(gp + 4);
        }

        // (5) MFMAs: 32 h + 4 x, fp16, 4 accumulator chains (depth 9)
        f32x4 acc[4];
#pragma unroll
        for (int i = 0; i < 4; ++i) acc[i] = (f32x4){0.f, 0.f, 0.f, 0.f};
#pragma unroll
        for (int kt = 0; kt < 32; ++kt) {
            f16x8 a = *(const f16x8*)(h_lds + (4 * kt + quad) * 128 + col * 8);
            acc[kt & 3] = __builtin_amdgcn_mfma_f32_16x16x32_f16(
                a, wh[kt], acc[kt & 3], 0, 0, 0);
        }
        const unsigned short* xrow = x_lds + col * 136;
#pragma unroll
        for (int kt = 0; kt < 4; ++kt) {
            f16x8 a = *(const f16x8*)(xrow + kt * 32 + quad * 8);
            acc[kt & 3] = __builtin_amdgcn_mfma_f32_16x16x32_f16(
                a, wi[kt], acc[kt & 3], 0, 0, 0);
        }

        // (6) epilogue: bias + tanh; pack fp16 pairs -> c_lds [16][36]
        float th[4];
#pragma unroll
        for (int i = 0; i < 4; ++i) {
            float pre = (acc[0][i] + acc[1][i]) + (acc[2][i] + acc[3][i])
                        + bias_sum;
            float pc  = fminf(fmaxf(pre, -9.f), 9.f);
            float e   = __expf(2.f * pc);
            th[i] = (e - 1.f) / (e + 1.f);
        }
        {
            unsigned int p01 = (unsigned int)f2h_bits(th[0]) |
                               ((unsigned int)f2h_bits(th[1]) << 16);
            unsigned int p23 = (unsigned int)f2h_bits(th[2]) |
                               ((unsigned int)f2h_bits(th[3]) << 16);
            unsigned int q01 = (unsigned int)__shfl_xor((int)p01, 1, 64);
            unsigned int q23 = (unsigned int)__shfl_xor((int)p23, 1, 64);
            if (!(lane & 1)) {
                unsigned int w0 = (p01 & 0xFFFFu) | (q01 << 16);
                unsigned int w1 = (p01 >> 16) | (q01 & 0xFFFF0000u);
                unsigned int w2 = (p23 & 0xFFFFu) | (q23 << 16);
                unsigned int w3 = (p23 >> 16) | (q23 & 0xFFFF0000u);
                const int c = wv * 8 + (col >> 1);
                unsigned int* cl = c_lds + (quad * 4) * 36 + c;
                cl[0]      = w0;
                cl[36]     = w1;
                cl[2 * 36] = w2;
                cl[3 * 36] = w3;
            }
        }
        if (t == TT - 1) {
#pragma unroll
            for (int i = 0; i < 4; ++i)
                out[(size_t)(m_base + quad * 4 + i) * HH + n_base + col] = th[i];
        }
        __syncthreads();

        // (7) publish via device-scope atomicExch (R11-verbatim), then
        //     ack -> barrier -> single padded flag (R11 ordering)
        if (t < TT - 1) {
            const int r  = tid >> 4;          // 0..15
            const int c0 = (tid & 15) * 2;    // 0,2,..,30
            unsigned int* dst = wbu + (size_t)(m * 16 + jj) * 512 + r * 32 + c0;
            atomicExch(dst,     c_lds[r * 36 + c0]);
            atomicExch(dst + 1, c_lds[r * 36 + c0 + 1]);
            asm volatile("s_waitcnt vmcnt(0)" ::: "memory");
            __syncthreads();
            if (tid == 0)
                atomicExch((unsigned int*)(flags + (m * 16 + jj) * 32),
                           (unsigned int)(t + 1));
        }
    }
}

extern "C" void kernel_launch(void* const* d_in, const int* in_sizes, int n_in,
                              void* d_out, int out_size, void* d_ws, size_t ws_size,
                              hipStream_t stream) {
    const float* x   = (const float*)d_in[0];
    const float* wih = (const float*)d_in[1];
    const float* whh = (const float*)d_in[2];
    const float* bih = (const float*)d_in[3];
    const float* bhh = (const float*)d_in[4];
    float* out = (float*)d_out;

    unsigned int* hbu0  = (unsigned int*)d_ws;                      // 128 KB
    unsigned int* hbu1  = hbu0 + 32768;                             // 128 KB
    unsigned int* flags = (unsigned int*)((char*)d_ws + 262144);    // 8 KB
    // flag slot: (m*16 + producer) * 32 dwords (128B padding per flag)

    // zero h buffers (h0 = 0) + padded flags (ws is poisoned 0xAA)
    hipMemsetAsync(d_ws, 0, 262144 + 8192, stream);

    esn_kernel<<<dim3(64), dim3(256), 0, stream>>>(x, wih, whh, bih, bhh,
                                                   out, hbu0, hbu1, flags);
}